// Round 9
// baseline (297.088 us; speedup 1.0000x reference)
//
#include <hip/hip_runtime.h>
#include <hip/hip_bf16.h>

#define N_NODES 50000
#define N_EDGES 600000
#define DIM_H   128
#define NPAD    50048   // N_NODES rounded up to 128 (DMA-safe zero tail)
#define NB_SCAN 196     // ceil(N_NODES / 256)

typedef __attribute__((ext_vector_type(8))) short bf16x8;   // 8 bf16 = 4 VGPRs
typedef __attribute__((ext_vector_type(4))) float f32x4;    // MFMA acc
typedef __attribute__((ext_vector_type(4))) short short4v;

__device__ __forceinline__ float b2f(__hip_bfloat16 x) { return __bfloat162float(x); }
__device__ __forceinline__ short f2bs(float f) {
    __hip_bfloat16 h = __float2bfloat16(f);   // RNE
    return *reinterpret_cast<short*>(&h);
}
__device__ __forceinline__ float bs2f(short s) {
    unsigned u = ((unsigned)(unsigned short)s) << 16;
    return __builtin_bit_cast(float, u);
}
__device__ __forceinline__ float sigm(float x) { return 1.f / (1.f + expf(-x)); }

// global -> LDS async DMA, 16 B per lane; LDS dst is wave-uniform base + lane*16.
__device__ __forceinline__ void dma16(const void* g, const void* lds_uniform) {
    __builtin_amdgcn_global_load_lds(
        (const __attribute__((address_space(1))) void*)g,
        (__attribute__((address_space(3))) void*)(unsigned)(unsigned long long)lds_uniform,
        16, 0, 0);
}

// ---------------------------------------------------------------------------
// K1: column sums of nodes + bf16 copy of nodes (each row visited exactly once)
// ---------------------------------------------------------------------------
__global__ __launch_bounds__(256) void colsum_k(const float* __restrict__ nodes,
                                                float* __restrict__ colsum,
                                                short* __restrict__ nodesB) {
    __shared__ float red[8][128];
    const int tid = threadIdx.x;
    const int cg = tid & 31;
    const int rl = tid >> 5;
    float4 acc = {0.f, 0.f, 0.f, 0.f};
    for (int r = blockIdx.x * 8 + rl; r < N_NODES; r += gridDim.x * 8) {
        float4 v = *(const float4*)(nodes + (size_t)r * DIM_H + cg * 4);
        acc.x += v.x; acc.y += v.y; acc.z += v.z; acc.w += v.w;
        *(short4v*)(nodesB + (size_t)r * DIM_H + cg * 4) =
            (short4v){f2bs(v.x), f2bs(v.y), f2bs(v.z), f2bs(v.w)};
    }
    *(float4*)&red[rl][cg * 4] = acc;
    __syncthreads();
    if (tid < 128) {
        float s = 0.f;
#pragma unroll
        for (int i = 0; i < 8; ++i) s += red[i][tid];
        unsafeAtomicAdd(&colsum[tid], s);
    }
}

// ---------------------------------------------------------------------------
// Weight f32 -> bf16 conversion
// ---------------------------------------------------------------------------
__global__ __launch_bounds__(256) void wcvt_k(const float* __restrict__ wmsg,
                                              const float* __restrict__ wih,
                                              const float* __restrict__ whh,
                                              short* __restrict__ wmsgB,
                                              short* __restrict__ wihB,
                                              short* __restrict__ whhB) {
    int i = blockIdx.x * 256 + threadIdx.x;
    if (i < 16384) wmsgB[i] = f2bs(wmsg[i]);
    if (i < 49152) { wihB[i] = f2bs(wih[i]); whhB[i] = f2bs(whh[i]); }
}

// ---------------------------------------------------------------------------
// CSR build: hist -> (bsum, scan2) -> reorder   (counting sort by dst)
// ---------------------------------------------------------------------------
__global__ __launch_bounds__(256) void hist_k(const int* __restrict__ edst,
                                              int* __restrict__ cnt) {
    int e = blockIdx.x * 256 + threadIdx.x;
    if (e < N_EDGES) atomicAdd(&cnt[edst[e]], 1);
}

__global__ __launch_bounds__(256) void bsum_k(const int* __restrict__ cnt,
                                              int* __restrict__ bsum) {
    const int t = threadIdx.x;
    int i = blockIdx.x * 256 + t;
    int v = (i < N_NODES) ? cnt[i] : 0;
#pragma unroll
    for (int o = 32; o; o >>= 1) v += __shfl_xor(v, o, 64);
    __shared__ int w4[4];
    if ((t & 63) == 0) w4[t >> 6] = v;
    __syncthreads();
    if (t == 0) bsum[blockIdx.x] = w4[0] + w4[1] + w4[2] + w4[3];
}

__global__ __launch_bounds__(256) void scan2_k(const int* __restrict__ cnt,
                                               const int* __restrict__ bsum,
                                               int* __restrict__ rowptr,
                                               int* __restrict__ pos) {
    const int b = blockIdx.x, t = threadIdx.x;
    const int lane = t & 63, w = t >> 6;
    __shared__ int red[4];
    __shared__ int wsum[4];

    int ov = (t < b) ? bsum[t] : 0;
#pragma unroll
    for (int o = 32; o; o >>= 1) ov += __shfl_xor(ov, o, 64);
    if (lane == 0) red[w] = ov;
    __syncthreads();
    const int offset = red[0] + red[1] + red[2] + red[3];

    int i = b * 256 + t;
    int v = (i < N_NODES) ? cnt[i] : 0;
    int x = v;
#pragma unroll
    for (int o = 1; o < 64; o <<= 1) {
        int y = __shfl_up(x, o, 64);
        if (lane >= o) x += y;
    }
    if (lane == 63) wsum[w] = x;
    __syncthreads();
    int woff = 0;
#pragma unroll
    for (int j = 0; j < 4; ++j)
        if (j < w) woff += wsum[j];
    int excl = offset + woff + (x - v);
    if (i < N_NODES) { rowptr[i] = excl; pos[i] = excl; }
    if (i == N_NODES - 1) rowptr[N_NODES] = excl + v;
}

__global__ __launch_bounds__(256) void reorder_k(const int* __restrict__ esrc,
                                                 const int* __restrict__ edst,
                                                 int* __restrict__ pos,
                                                 int* __restrict__ ssrc) {
    int e = blockIdx.x * 256 + threadIdx.x;
    if (e < N_EDGES) {
        int p = atomicAdd(&pos[edst[e]], 1);
        ssrc[p] = esrc[e];
    }
}

// ---------------------------------------------------------------------------
// K2': gather-aggregate  aggB[n] = bf16( sum_{e in row n} nodesB[ssrc[e]] )
// ---------------------------------------------------------------------------
__global__ __launch_bounds__(256) void aggregate_k(const short* __restrict__ nodesB,
                                                   const int* __restrict__ rowptr,
                                                   const int* __restrict__ ssrc,
                                                   short* __restrict__ aggB) {
    const int wid = threadIdx.x >> 6;
    const int lane = threadIdx.x & 63;
    const int n = blockIdx.x * 4 + wid;
    if (n >= N_NODES) return;
    const int s0 = rowptr[n], s1 = rowptr[n + 1];
    float2 acc = {0.f, 0.f};
    int e = s0;
    for (; e + 3 < s1; e += 4) {
        int sa = ssrc[e], sb = ssrc[e + 1], sc = ssrc[e + 2], sd = ssrc[e + 3];
        short2 va = ((const short2*)(nodesB + (size_t)sa * DIM_H))[lane];
        short2 vb = ((const short2*)(nodesB + (size_t)sb * DIM_H))[lane];
        short2 vc = ((const short2*)(nodesB + (size_t)sc * DIM_H))[lane];
        short2 vd = ((const short2*)(nodesB + (size_t)sd * DIM_H))[lane];
        acc.x += (bs2f(va.x) + bs2f(vb.x)) + (bs2f(vc.x) + bs2f(vd.x));
        acc.y += (bs2f(va.y) + bs2f(vb.y)) + (bs2f(vc.y) + bs2f(vd.y));
    }
    for (; e < s1; ++e) {
        int sa = ssrc[e];
        short2 va = ((const short2*)(nodesB + (size_t)sa * DIM_H))[lane];
        acc.x += bs2f(va.x);
        acc.y += bs2f(va.y);
    }
    short2 o; o.x = f2bs(acc.x); o.y = f2bs(acc.y);
    ((short2*)(aggB + (size_t)n * DIM_H))[lane] = o;
}

// ---------------------------------------------------------------------------
// MFMA helpers: XOR-swizzled 16B-granule staging + 64x64 wave GEMM
// ---------------------------------------------------------------------------
__device__ __forceinline__ void stage_tile(const short* __restrict__ src, int row0,
                                           short* lds, int w, int lane) {
#pragma unroll
    for (int it = 0; it < 8; ++it) {
        int c = w * 8 + it;
        int s = c * 64 + lane;          // granule slot (16B units)
        int r = s >> 4, q = s & 15;
        int g = q ^ (r & 15);           // which global granule lives in slot q
        dma16(src + (((size_t)(row0 + r)) << 7) + (g << 3), lds + (size_t)c * 512);
    }
}

__device__ __forceinline__ void wave_mm(const short* __restrict__ A,
                                        const short* __restrict__ W,
                                        f32x4 (&acc)[4][4],
                                        int wm, int wn, int r16, int half) {
#pragma unroll
    for (int kt = 0; kt < 4; ++kt) {
        const int sq = ((kt * 4 + half) ^ r16) << 3;
        bf16x8 af[4], bfr[4];
#pragma unroll
        for (int t = 0; t < 4; ++t) {
            af[t]  = *(const bf16x8*)&A[(wm + t * 16 + r16) * 128 + sq];
            bfr[t] = *(const bf16x8*)&W[(wn + t * 16 + r16) * 128 + sq];
        }
#pragma unroll
        for (int i = 0; i < 4; ++i)
#pragma unroll
            for (int j = 0; j < 4; ++j)
                acc[i][j] = __builtin_amdgcn_mfma_f32_16x16x32_bf16(
                    af[i], bfr[j], acc[i][j], 0, 0, 0);
    }
}

// swizzled LDS index of bf16 element (row, col) in a staged tile
__device__ __forceinline__ int swz(int row, int col) {
    int g = (col >> 3) ^ (row & 15);
    return row * 128 + (g << 3) + (col & 7);
}

// msgin GEMM:  msginB = bf16( aggB @ WmsgB^T + deg*b_msg + mean )
__global__ __launch_bounds__(256) void mgemm0_k(const short* __restrict__ aggB,
                                                const short* __restrict__ wmsgB,
                                                const float* __restrict__ bmsg,
                                                const int* __restrict__ degi,
                                                const float* __restrict__ colsum,
                                                short* __restrict__ msginB) {
    __shared__ short As[128 * 128];
    __shared__ short Ws[128 * 128];
    const int tid = threadIdx.x;
    const int lane = tid & 63, w = tid >> 6;
    const int m0 = blockIdx.x * 128;

    stage_tile(aggB, m0, As, w, lane);
    stage_tile(wmsgB, 0, Ws, w, lane);
    __syncthreads();

    const int r16 = lane & 15, half = lane >> 4;
    const int wm = (w >> 1) * 64, wn = (w & 1) * 64;
    f32x4 acc[4][4] = {};
    wave_mm(As, Ws, acc, wm, wn, r16, half);

#pragma unroll
    for (int i = 0; i < 4; ++i)
#pragma unroll
        for (int r = 0; r < 4; ++r) {
            int m = m0 + wm + i * 16 + half * 4 + r;
            if (m < N_NODES) {
#pragma unroll
                for (int j = 0; j < 4; ++j) {
                    int n = wn + j * 16 + r16;
                    float c = acc[i][j][r] + (float)degi[m] * bmsg[n]
                            + colsum[n] * (1.0f / N_NODES);
                    msginB[(size_t)m * 128 + n] = f2bs(c);
                }
            }
        }
}

// ---------------------------------------------------------------------------
// Fused GRU GEMMs + gates + LayerNorm + residual.
// Block = 128 nodes. A-tiles (msginB, nodesB) staged once; W-pair restaged
// per gate (r -> n -> z). h' -> LDS (aliases dead W buffer), row-LN, write f32.
// LDS: 32+32+64 = 128 KB -> 1 block/CU. acc peak ~192 VGPR -> launch_bounds(256,1).
// ---------------------------------------------------------------------------
__global__ __launch_bounds__(256, 1) void grufuse_k(const short* __restrict__ msginB,
                                                    const short* __restrict__ nodesB,
                                                    const short* __restrict__ wihB,
                                                    const short* __restrict__ whhB,
                                                    const float* __restrict__ bih,
                                                    const float* __restrict__ bhh,
                                                    const float* __restrict__ colsum,
                                                    const float* __restrict__ gamma,
                                                    const float* __restrict__ beta,
                                                    float* __restrict__ out) {
    __shared__ short Am[128 * 128];     // msgin tile (bf16, swizzled)
    __shared__ short An[128 * 128];     // nodes tile
    __shared__ short Wbuf[2 * 128 * 128];  // Wi | Wh ; aliased as f32 hbuf later
    short* Wi = Wbuf;
    short* Wh = Wbuf + 128 * 128;
    float* hbuf = (float*)Wbuf;         // 128x128 f32 = 64 KB (exact alias)

    const int tid = threadIdx.x;
    const int lane = tid & 63, w = tid >> 6;
    const int m0 = blockIdx.x * 128;
    const int r16 = lane & 15, half = lane >> 4;
    const int wm = (w >> 1) * 64, wn = (w & 1) * 64;

    // ---- stage A tiles + r-gate weights (gate layout: r=0, z=128, n=256) ----
    stage_tile(msginB, m0, Am, w, lane);
    stage_tile(nodesB, m0, An, w, lane);
    stage_tile(wihB, 0, Wi, w, lane);
    stage_tile(whhB, 0, Wh, w, lane);
    __syncthreads();

    // ---- r gate (K=256: msgin@wih_r + nodes@whh_r) ----
    f32x4 rA[4][4] = {};
    wave_mm(Am, Wi, rA, wm, wn, r16, half);
    wave_mm(An, Wh, rA, wm, wn, r16, half);
    __syncthreads();                       // all waves done reading Wi/Wh
    stage_tile(wihB, 256, Wi, w, lane);    // n gate (DMA overlaps r-sigmoid)
    stage_tile(whhB, 256, Wh, w, lane);
    {
        float bj[4];
#pragma unroll
        for (int j = 0; j < 4; ++j) {
            int c = wn + j * 16 + r16;
            bj[j] = bih[c] + bhh[c];
        }
#pragma unroll
        for (int i = 0; i < 4; ++i)
#pragma unroll
            for (int j = 0; j < 4; ++j)
#pragma unroll
                for (int r = 0; r < 4; ++r)
                    rA[i][j][r] = sigm(rA[i][j][r] + bj[j]);
    }
    __syncthreads();                       // n-gate weights landed

    // ---- n gate pieces ----
    f32x4 inA[4][4] = {};
    wave_mm(Am, Wi, inA, wm, wn, r16, half);
    f32x4 hnA[4][4] = {};
    wave_mm(An, Wh, hnA, wm, wn, r16, half);
    __syncthreads();
    stage_tile(wihB, 128, Wi, w, lane);    // z gate (DMA overlaps tanh)
    stage_tile(whhB, 128, Wh, w, lane);
    {
        float bi[4], bh[4];
#pragma unroll
        for (int j = 0; j < 4; ++j) {
            int c = wn + j * 16 + r16;
            bi[j] = bih[256 + c];
            bh[j] = bhh[256 + c];
        }
#pragma unroll
        for (int i = 0; i < 4; ++i)
#pragma unroll
            for (int j = 0; j < 4; ++j)
#pragma unroll
                for (int r = 0; r < 4; ++r)
                    inA[i][j][r] = tanhf(inA[i][j][r] + bi[j] +
                                         rA[i][j][r] * (hnA[i][j][r] + bh[j]));
        // inA now holds n; rA/hnA dead
    }
    __syncthreads();                       // z-gate weights landed

    // ---- z gate (K=256) ----
    f32x4 zA[4][4] = {};
    wave_mm(Am, Wi, zA, wm, wn, r16, half);
    wave_mm(An, Wh, zA, wm, wn, r16, half);
    __syncthreads();                       // done reading Wbuf: safe to alias hbuf

    // ---- combine: h' = (1-z)*n + z*h  -> hbuf ----
    {
        float bj[4];
#pragma unroll
        for (int j = 0; j < 4; ++j) {
            int c = wn + j * 16 + r16;
            bj[j] = bih[128 + c] + bhh[128 + c];
        }
#pragma unroll
        for (int i = 0; i < 4; ++i)
#pragma unroll
            for (int r = 0; r < 4; ++r) {
                int row = wm + i * 16 + half * 4 + r;
#pragma unroll
                for (int j = 0; j < 4; ++j) {
                    int col = wn + j * 16 + r16;
                    float z = sigm(zA[i][j][r] + bj[j]);
                    float h = bs2f(An[swz(row, col)]);
                    hbuf[row * 128 + col] = (1.f - z) * inA[i][j][r] + z * h;
                }
            }
    }
    __syncthreads();

    // ---- LayerNorm + residual + store: wave w owns rows w*32 .. w*32+31 ----
    {
        float ga = gamma[lane], gb = gamma[lane + 64];
        float ba = beta[lane],  bb = beta[lane + 64];
        float ca = colsum[lane] * (1.0f / N_NODES);
        float cb = colsum[lane + 64] * (1.0f / N_NODES);
        for (int rr = 0; rr < 32; ++rr) {
            int row = w * 32 + rr;
            int gm = m0 + row;
            float a = hbuf[row * 128 + lane];
            float b = hbuf[row * 128 + 64 + lane];
            float s = a + b, q = a * a + b * b;
#pragma unroll
            for (int o = 32; o; o >>= 1) {
                s += __shfl_xor(s, o, 64);
                q += __shfl_xor(q, o, 64);
            }
            float mu = s * (1.0f / 128.0f);
            float var = q * (1.0f / 128.0f) - mu * mu;
            float rstd = rsqrtf(var + 1e-5f);
            if (gm < N_NODES) {
                float ma = bs2f(Am[swz(row, lane)]) - ca;        // messages residual
                float mb = bs2f(Am[swz(row, lane + 64)]) - cb;
                out[(size_t)gm * 128 + lane]      = ga * (a - mu) * rstd + ba + ma;
                out[(size_t)gm * 128 + 64 + lane] = gb * (b - mu) * rstd + bb + mb;
            }
        }
    }
}

// ---------------------------------------------------------------------------
extern "C" void kernel_launch(void* const* d_in, const int* in_sizes, int n_in,
                              void* d_out, int out_size, void* d_ws, size_t ws_size,
                              hipStream_t stream) {
    const float* nodes = (const float*)d_in[0];
    const float* Wmsg  = (const float*)d_in[1];
    const float* bmsg  = (const float*)d_in[2];
    const float* wih   = (const float*)d_in[3];
    const float* whh   = (const float*)d_in[4];
    const float* bih   = (const float*)d_in[5];
    const float* bhh   = (const float*)d_in[6];
    const float* gamma = (const float*)d_in[7];
    const float* beta  = (const float*)d_in[8];
    const int* esrc = (const int*)d_in[9];
    const int* edst = (const int*)d_in[10];
    float* out = (float*)d_out;

    // workspace layout (~41.7 MB, no aliasing needed anymore)
    char* ws = (char*)d_ws;
    short* aggB   = (short*)ws;                        // NPAD*128*2 = 12.81 MB
    short* nodesB = (short*)(ws + 12812288);           // 12.81 MB
    short* msginB = (short*)(ws + 25624576);           // 12.81 MB
    short* wmsgB  = (short*)(ws + 38436864);           // 32 KB
    short* wihB   = (short*)(ws + 38469632);           // 96 KB
    short* whhB   = (short*)(ws + 38567936);           // 96 KB
    float* colsum = (float*)(ws + 38666240);           // 512 B
    int*   cnt    = (int*)(ws + 38666752);             // 200 KB
    int*   rowptr = (int*)(ws + 38866752);             // 200 KB + 4 (pad to 8)
    int*   pos    = (int*)(ws + 39066760);             // 200 KB
    int*   ssrc   = (int*)(ws + 39266760);             // 2.4 MB -> end ~41.7 MB
    int*   bsum   = pos;  // scratch overlap is fine: bsum consumed by scan2 which writes pos afterward? NO -- keep separate:
    bsum          = (int*)(ws + 41666760);             // 784 B -> end 41,667,544

    hipMemsetAsync(cnt, 0, N_NODES * sizeof(int), stream);
    hipMemsetAsync(colsum, 0, DIM_H * sizeof(float), stream);
    // zero the 48 padded tail rows of each DMA-read bf16 matrix
    hipMemsetAsync(ws + (size_t)N_NODES * 256, 0, (NPAD - N_NODES) * 256, stream);            // aggB tail
    hipMemsetAsync(ws + 12812288 + (size_t)N_NODES * 256, 0, (NPAD - N_NODES) * 256, stream); // nodesB tail
    hipMemsetAsync(ws + 25624576 + (size_t)N_NODES * 256, 0, (NPAD - N_NODES) * 256, stream); // msginB tail

    colsum_k<<<512, 256, 0, stream>>>(nodes, colsum, nodesB);
    wcvt_k<<<192, 256, 0, stream>>>(Wmsg, wih, whh, wmsgB, wihB, whhB);

    const int EB = (N_EDGES + 255) / 256;
    hist_k<<<EB, 256, 0, stream>>>(edst, cnt);
    bsum_k<<<NB_SCAN, 256, 0, stream>>>(cnt, bsum);
    scan2_k<<<NB_SCAN, 256, 0, stream>>>(cnt, bsum, rowptr, pos);
    reorder_k<<<EB, 256, 0, stream>>>(esrc, edst, pos, ssrc);
    aggregate_k<<<(N_NODES + 3) / 4, 256, 0, stream>>>(nodesB, rowptr, ssrc, aggB);

    const int MB2 = (N_NODES + 127) / 128;  // 391
    mgemm0_k<<<dim3(MB2, 1), 256, 0, stream>>>(aggB, wmsgB, bmsg, cnt, colsum, msginB);
    grufuse_k<<<MB2, 256, 0, stream>>>(msginB, nodesB, wihB, whhB, bih, bhh,
                                       colsum, gamma, beta, out);
}

// Round 10
// 271.077 us; speedup vs baseline: 1.0960x; 1.0960x over previous
//
#include <hip/hip_runtime.h>
#include <hip/hip_bf16.h>

#define N_NODES 50000
#define N_EDGES 600000
#define DIM_H   128
#define NPAD    50048   // N_NODES rounded up to 128 (DMA-safe zero tail)
#define NB_SCAN 196     // ceil(N_NODES / 256)

typedef __attribute__((ext_vector_type(8))) short bf16x8;   // 8 bf16 = 4 VGPRs
typedef __attribute__((ext_vector_type(4))) float f32x4;    // MFMA acc
typedef __attribute__((ext_vector_type(4))) short short4v;

__device__ __forceinline__ short f2bs(float f) {
    __hip_bfloat16 h = __float2bfloat16(f);   // RNE
    return *reinterpret_cast<short*>(&h);
}
__device__ __forceinline__ float bs2f(short s) {
    unsigned u = ((unsigned)(unsigned short)s) << 16;
    return __builtin_bit_cast(float, u);
}
__device__ __forceinline__ float sigm(float x) { return 1.f / (1.f + expf(-x)); }

// global -> LDS async DMA, 16 B per lane; LDS dst is wave-uniform base + lane*16.
__device__ __forceinline__ void dma16(const void* g, const void* lds_uniform) {
    __builtin_amdgcn_global_load_lds(
        (const __attribute__((address_space(1))) void*)g,
        (__attribute__((address_space(3))) void*)(unsigned)(unsigned long long)lds_uniform,
        16, 0, 0);
}

// ---------------------------------------------------------------------------
// K0: prep — weight bf16 conversion + zero cnt/colsum/padded-tails
// (absorbs 5 hipMemsetAsync dispatches; 196 blocks x 256 = 50176 threads)
// ---------------------------------------------------------------------------
__global__ __launch_bounds__(256) void prep_k(const float* __restrict__ wmsg,
                                              const float* __restrict__ wih,
                                              const float* __restrict__ whh,
                                              short* __restrict__ wmsgB,
                                              short* __restrict__ wihB,
                                              short* __restrict__ whhB,
                                              int* __restrict__ cnt,
                                              float* __restrict__ colsum,
                                              short* __restrict__ aggTail,
                                              short* __restrict__ nodesTail,
                                              short* __restrict__ msginTail) {
    int i = blockIdx.x * 256 + threadIdx.x;
    if (i < 16384) wmsgB[i] = f2bs(wmsg[i]);
    if (i < 49152) { wihB[i] = f2bs(wih[i]); whhB[i] = f2bs(whh[i]); }
    if (i < N_NODES) cnt[i] = 0;
    if (i < 128) colsum[i] = 0.f;
    if (i < 1536) {           // 48 rows x 128 shorts = 6144 shorts = 1536 short4
        short4v z = {0, 0, 0, 0};
        *(short4v*)(aggTail   + i * 4) = z;
        *(short4v*)(nodesTail + i * 4) = z;
        *(short4v*)(msginTail + i * 4) = z;
    }
}

// ---------------------------------------------------------------------------
// K1: column sums of nodes + bf16 copy of nodes (each row visited exactly once)
// ---------------------------------------------------------------------------
__global__ __launch_bounds__(256) void colsum_k(const float* __restrict__ nodes,
                                                float* __restrict__ colsum,
                                                short* __restrict__ nodesB) {
    __shared__ float red[8][128];
    const int tid = threadIdx.x;
    const int cg = tid & 31;
    const int rl = tid >> 5;
    float4 acc = {0.f, 0.f, 0.f, 0.f};
    for (int r = blockIdx.x * 8 + rl; r < N_NODES; r += gridDim.x * 8) {
        float4 v = *(const float4*)(nodes + (size_t)r * DIM_H + cg * 4);
        acc.x += v.x; acc.y += v.y; acc.z += v.z; acc.w += v.w;
        *(short4v*)(nodesB + (size_t)r * DIM_H + cg * 4) =
            (short4v){f2bs(v.x), f2bs(v.y), f2bs(v.z), f2bs(v.w)};
    }
    *(float4*)&red[rl][cg * 4] = acc;
    __syncthreads();
    if (tid < 128) {
        float s = 0.f;
#pragma unroll
        for (int i = 0; i < 8; ++i) s += red[i][tid];
        unsafeAtomicAdd(&colsum[tid], s);
    }
}

// ---------------------------------------------------------------------------
// CSR build: hist -> (bsum, scan2) -> reorder   (counting sort by dst)
// ---------------------------------------------------------------------------
__global__ __launch_bounds__(256) void hist_k(const int* __restrict__ edst,
                                              int* __restrict__ cnt) {
    int e = blockIdx.x * 256 + threadIdx.x;
    if (e < N_EDGES) atomicAdd(&cnt[edst[e]], 1);
}

__global__ __launch_bounds__(256) void bsum_k(const int* __restrict__ cnt,
                                              int* __restrict__ bsum) {
    const int t = threadIdx.x;
    int i = blockIdx.x * 256 + t;
    int v = (i < N_NODES) ? cnt[i] : 0;
#pragma unroll
    for (int o = 32; o; o >>= 1) v += __shfl_xor(v, o, 64);
    __shared__ int w4[4];
    if ((t & 63) == 0) w4[t >> 6] = v;
    __syncthreads();
    if (t == 0) bsum[blockIdx.x] = w4[0] + w4[1] + w4[2] + w4[3];
}

__global__ __launch_bounds__(256) void scan2_k(const int* __restrict__ cnt,
                                               const int* __restrict__ bsum,
                                               int* __restrict__ rowptr,
                                               int* __restrict__ pos) {
    const int b = blockIdx.x, t = threadIdx.x;
    const int lane = t & 63, w = t >> 6;
    __shared__ int red[4];
    __shared__ int wsum[4];

    int ov = (t < b) ? bsum[t] : 0;
#pragma unroll
    for (int o = 32; o; o >>= 1) ov += __shfl_xor(ov, o, 64);
    if (lane == 0) red[w] = ov;
    __syncthreads();
    const int offset = red[0] + red[1] + red[2] + red[3];

    int i = b * 256 + t;
    int v = (i < N_NODES) ? cnt[i] : 0;
    int x = v;
#pragma unroll
    for (int o = 1; o < 64; o <<= 1) {
        int y = __shfl_up(x, o, 64);
        if (lane >= o) x += y;
    }
    if (lane == 63) wsum[w] = x;
    __syncthreads();
    int woff = 0;
#pragma unroll
    for (int j = 0; j < 4; ++j)
        if (j < w) woff += wsum[j];
    int excl = offset + woff + (x - v);
    if (i < N_NODES) { rowptr[i] = excl; pos[i] = excl; }
    if (i == N_NODES - 1) rowptr[N_NODES] = excl + v;
}

__global__ __launch_bounds__(256) void reorder_k(const int* __restrict__ esrc,
                                                 const int* __restrict__ edst,
                                                 int* __restrict__ pos,
                                                 int* __restrict__ ssrc) {
    int e = blockIdx.x * 256 + threadIdx.x;
    if (e < N_EDGES) {
        int p = atomicAdd(&pos[edst[e]], 1);
        ssrc[p] = esrc[e];
    }
}

// ---------------------------------------------------------------------------
// K2': gather-aggregate  aggB[n] = bf16( sum_{e in row n} nodesB[ssrc[e]] )
// ---------------------------------------------------------------------------
__global__ __launch_bounds__(256) void aggregate_k(const short* __restrict__ nodesB,
                                                   const int* __restrict__ rowptr,
                                                   const int* __restrict__ ssrc,
                                                   short* __restrict__ aggB) {
    const int wid = threadIdx.x >> 6;
    const int lane = threadIdx.x & 63;
    const int n = blockIdx.x * 4 + wid;
    if (n >= N_NODES) return;
    const int s0 = rowptr[n], s1 = rowptr[n + 1];
    float2 acc = {0.f, 0.f};
    int e = s0;
    for (; e + 3 < s1; e += 4) {
        int sa = ssrc[e], sb = ssrc[e + 1], sc = ssrc[e + 2], sd = ssrc[e + 3];
        short2 va = ((const short2*)(nodesB + (size_t)sa * DIM_H))[lane];
        short2 vb = ((const short2*)(nodesB + (size_t)sb * DIM_H))[lane];
        short2 vc = ((const short2*)(nodesB + (size_t)sc * DIM_H))[lane];
        short2 vd = ((const short2*)(nodesB + (size_t)sd * DIM_H))[lane];
        acc.x += (bs2f(va.x) + bs2f(vb.x)) + (bs2f(vc.x) + bs2f(vd.x));
        acc.y += (bs2f(va.y) + bs2f(vb.y)) + (bs2f(vc.y) + bs2f(vd.y));
    }
    for (; e < s1; ++e) {
        int sa = ssrc[e];
        short2 va = ((const short2*)(nodesB + (size_t)sa * DIM_H))[lane];
        acc.x += bs2f(va.x);
        acc.y += bs2f(va.y);
    }
    short2 o; o.x = f2bs(acc.x); o.y = f2bs(acc.y);
    ((short2*)(aggB + (size_t)n * DIM_H))[lane] = o;
}

// ---------------------------------------------------------------------------
// MFMA helpers: XOR-swizzled 16B-granule staging + 64x64 wave GEMM
// ---------------------------------------------------------------------------
__device__ __forceinline__ void stage_tile(const short* __restrict__ src, int row0,
                                           short* lds, int w, int lane) {
#pragma unroll
    for (int it = 0; it < 8; ++it) {
        int c = w * 8 + it;
        int s = c * 64 + lane;          // granule slot (16B units)
        int r = s >> 4, q = s & 15;
        int g = q ^ (r & 15);           // which global granule lives in slot q
        dma16(src + (((size_t)(row0 + r)) << 7) + (g << 3), lds + (size_t)c * 512);
    }
}

__device__ __forceinline__ void wave_mm(const short* __restrict__ A,
                                        const short* __restrict__ W,
                                        f32x4 (&acc)[4][4],
                                        int wm, int wn, int r16, int half) {
#pragma unroll
    for (int kt = 0; kt < 4; ++kt) {
        const int sq = ((kt * 4 + half) ^ r16) << 3;
        bf16x8 af[4], bfr[4];
#pragma unroll
        for (int t = 0; t < 4; ++t) {
            af[t]  = *(const bf16x8*)&A[(wm + t * 16 + r16) * 128 + sq];
            bfr[t] = *(const bf16x8*)&W[(wn + t * 16 + r16) * 128 + sq];
        }
#pragma unroll
        for (int i = 0; i < 4; ++i)
#pragma unroll
            for (int j = 0; j < 4; ++j)
                acc[i][j] = __builtin_amdgcn_mfma_f32_16x16x32_bf16(
                    af[i], bfr[j], acc[i][j], 0, 0, 0);
    }
}

// msgin GEMM:  msginB = bf16( aggB @ WmsgB^T + deg*b_msg + mean )
__global__ __launch_bounds__(256) void mgemm0_k(const short* __restrict__ aggB,
                                                const short* __restrict__ wmsgB,
                                                const float* __restrict__ bmsg,
                                                const int* __restrict__ degi,
                                                const float* __restrict__ colsum,
                                                short* __restrict__ msginB) {
    __shared__ short As[128 * 128];
    __shared__ short Ws[128 * 128];
    const int tid = threadIdx.x;
    const int lane = tid & 63, w = tid >> 6;
    const int m0 = blockIdx.x * 128;

    stage_tile(aggB, m0, As, w, lane);
    stage_tile(wmsgB, 0, Ws, w, lane);
    __syncthreads();

    const int r16 = lane & 15, half = lane >> 4;
    const int wm = (w >> 1) * 64, wn = (w & 1) * 64;
    f32x4 acc[4][4] = {};
    wave_mm(As, Ws, acc, wm, wn, r16, half);

#pragma unroll
    for (int i = 0; i < 4; ++i)
#pragma unroll
        for (int r = 0; r < 4; ++r) {
            int m = m0 + wm + i * 16 + half * 4 + r;
            if (m < N_NODES) {
#pragma unroll
                for (int j = 0; j < 4; ++j) {
                    int n = wn + j * 16 + r16;
                    float c = acc[i][j][r] + (float)degi[m] * bmsg[n]
                            + colsum[n] * (1.0f / N_NODES);
                    msginB[(size_t)m * 128 + n] = f2bs(c);
                }
            }
        }
}

// merged gi/gh GEMM: y<3 -> gi = msginB@wihB^T + b_ih ; y>=3 -> gh = nodesB@whhB^T + b_hh
__global__ __launch_bounds__(256) void gigh_k(const short* __restrict__ msginB,
                                              const short* __restrict__ nodesB,
                                              const short* __restrict__ wihB,
                                              const short* __restrict__ whhB,
                                              const float* __restrict__ bih,
                                              const float* __restrict__ bhh,
                                              short* __restrict__ gi,
                                              short* __restrict__ gh) {
    __shared__ short As[128 * 128];
    __shared__ short Ws[128 * 128];
    const int tid = threadIdx.x;
    const int lane = tid & 63, w = tid >> 6;
    const int m0 = blockIdx.x * 128;
    const int y = blockIdx.y;
    const short* A; const short* W; const float* bias; short* out; int n0;
    if (y < 3) { A = msginB; W = wihB; bias = bih; out = gi; n0 = y * 128; }
    else       { A = nodesB; W = whhB; bias = bhh; out = gh; n0 = (y - 3) * 128; }

    stage_tile(A, m0, As, w, lane);
    stage_tile(W, n0, Ws, w, lane);
    __syncthreads();

    const int r16 = lane & 15, half = lane >> 4;
    const int wm = (w >> 1) * 64, wn = (w & 1) * 64;
    f32x4 acc[4][4] = {};
    wave_mm(As, Ws, acc, wm, wn, r16, half);

#pragma unroll
    for (int i = 0; i < 4; ++i)
#pragma unroll
        for (int r = 0; r < 4; ++r) {
            int m = m0 + wm + i * 16 + half * 4 + r;
            if (m < N_NODES) {
#pragma unroll
                for (int j = 0; j < 4; ++j) {
                    int n = n0 + wn + j * 16 + r16;
                    out[(size_t)m * 384 + n] = f2bs(acc[i][j][r] + bias[n]);
                }
            }
        }
}

// ---------------------------------------------------------------------------
// K5: GRU gates + LayerNorm + residual. One wave per node; short2/float2
// vectorized (lane owns cols 2l, 2l+1).
// ---------------------------------------------------------------------------
__global__ __launch_bounds__(256) void fuse_k(const short* __restrict__ nodesB,
                                              const short* __restrict__ gi,
                                              const short* __restrict__ gh,
                                              const short* __restrict__ msginB,
                                              const float* __restrict__ colsum,
                                              const float* __restrict__ gamma,
                                              const float* __restrict__ beta,
                                              float* __restrict__ out) {
    const int wid = threadIdx.x >> 6;
    const int lane = threadIdx.x & 63;
    const int n = blockIdx.x * 4 + wid;
    if (n >= N_NODES) return;

    const short* gir = gi + (size_t)n * 384;
    const short* ghr = gh + (size_t)n * 384;

    short2 ir2 = ((const short2*)gir)[lane];
    short2 iz2 = ((const short2*)(gir + 128))[lane];
    short2 in2 = ((const short2*)(gir + 256))[lane];
    short2 hr2 = ((const short2*)ghr)[lane];
    short2 hz2 = ((const short2*)(ghr + 128))[lane];
    short2 hn2 = ((const short2*)(ghr + 256))[lane];
    short2 h2  = ((const short2*)(nodesB + (size_t)n * DIM_H))[lane];
    short2 mi2 = ((const short2*)(msginB + (size_t)n * DIM_H))[lane];
    float2 cs2 = ((const float2*)colsum)[lane];
    float2 ga2 = ((const float2*)gamma)[lane];
    float2 be2 = ((const float2*)beta)[lane];

    float hn[2], resid[2];
    {
        float r = sigm(bs2f(ir2.x) + bs2f(hr2.x));
        float z = sigm(bs2f(iz2.x) + bs2f(hz2.x));
        float ng = tanhf(bs2f(in2.x) + r * bs2f(hn2.x));
        hn[0] = (1.f - z) * ng + z * bs2f(h2.x);
        resid[0] = bs2f(mi2.x) - cs2.x * (1.0f / N_NODES);
    }
    {
        float r = sigm(bs2f(ir2.y) + bs2f(hr2.y));
        float z = sigm(bs2f(iz2.y) + bs2f(hz2.y));
        float ng = tanhf(bs2f(in2.y) + r * bs2f(hn2.y));
        hn[1] = (1.f - z) * ng + z * bs2f(h2.y);
        resid[1] = bs2f(mi2.y) - cs2.y * (1.0f / N_NODES);
    }
    float s = hn[0] + hn[1];
    float q = hn[0] * hn[0] + hn[1] * hn[1];
#pragma unroll
    for (int o = 32; o; o >>= 1) {
        s += __shfl_xor(s, o, 64);
        q += __shfl_xor(q, o, 64);
    }
    float mu = s * (1.0f / DIM_H);
    float var = q * (1.0f / DIM_H) - mu * mu;
    float rstd = rsqrtf(var + 1e-5f);
    float2 o2;
    o2.x = ga2.x * (hn[0] - mu) * rstd + be2.x + resid[0];
    o2.y = ga2.y * (hn[1] - mu) * rstd + be2.y + resid[1];
    ((float2*)(out + (size_t)n * DIM_H))[lane] = o2;
}

// ---------------------------------------------------------------------------
extern "C" void kernel_launch(void* const* d_in, const int* in_sizes, int n_in,
                              void* d_out, int out_size, void* d_ws, size_t ws_size,
                              hipStream_t stream) {
    const float* nodes = (const float*)d_in[0];
    const float* Wmsg  = (const float*)d_in[1];
    const float* bmsg  = (const float*)d_in[2];
    const float* wih   = (const float*)d_in[3];
    const float* whh   = (const float*)d_in[4];
    const float* bih   = (const float*)d_in[5];
    const float* bhh   = (const float*)d_in[6];
    const float* gamma = (const float*)d_in[7];
    const float* beta  = (const float*)d_in[8];
    const int* esrc = (const int*)d_in[9];
    const int* edst = (const int*)d_in[10];
    float* out = (float*)d_out;

    // workspace layout (~118.5 MB; harness poisons ~268 MB so ws_size is ample)
    char* ws = (char*)d_ws;
    short* gi_s   = (short*)ws;                        // 38.4 MB
    short* gh_s   = (short*)(ws + 38400000);           // 38.4 MB
    short* aggB   = (short*)(ws + 76800000);           // NPAD*256 = 12.81 MB
    short* nodesB = (short*)(ws + 89612288);           // 12.81 MB
    short* msginB = (short*)(ws + 102424576);          // 12.81 MB
    short* wmsgB  = (short*)(ws + 115236864);          // 32 KB
    short* wihB   = (short*)(ws + 115269632);          // 96 KB
    short* whhB   = (short*)(ws + 115367936);          // 96 KB
    float* colsum = (float*)(ws + 115466240);          // 512 B
    int*   cnt    = (int*)(ws + 115466752);            // 200 KB
    int*   rowptr = (int*)(ws + 115666752);            // 200 KB + 8
    int*   pos    = (int*)(ws + 115866760);            // 200 KB
    int*   ssrc   = (int*)(ws + 116066760);            // 2.4 MB
    int*   bsum   = (int*)(ws + 118466760);            // 784 B -> end ~118.47 MB

    short* aggTail   = aggB   + (size_t)N_NODES * DIM_H;
    short* nodesTail = nodesB + (size_t)N_NODES * DIM_H;
    short* msginTail = msginB + (size_t)N_NODES * DIM_H;

    prep_k<<<NB_SCAN, 256, 0, stream>>>(Wmsg, wih, whh, wmsgB, wihB, whhB,
                                        cnt, colsum, aggTail, nodesTail, msginTail);
    colsum_k<<<512, 256, 0, stream>>>(nodes, colsum, nodesB);

    const int EB = (N_EDGES + 255) / 256;
    hist_k<<<EB, 256, 0, stream>>>(edst, cnt);
    bsum_k<<<NB_SCAN, 256, 0, stream>>>(cnt, bsum);
    scan2_k<<<NB_SCAN, 256, 0, stream>>>(cnt, bsum, rowptr, pos);
    reorder_k<<<EB, 256, 0, stream>>>(esrc, edst, pos, ssrc);
    aggregate_k<<<(N_NODES + 3) / 4, 256, 0, stream>>>(nodesB, rowptr, ssrc, aggB);

    const int MB2 = (N_NODES + 127) / 128;  // 391
    mgemm0_k<<<dim3(MB2, 1), 256, 0, stream>>>(aggB, wmsgB, bmsg, cnt, colsum, msginB);
    gigh_k<<<dim3(MB2, 6), 256, 0, stream>>>(msginB, nodesB, wihB, whhB, bih, bhh,
                                             gi_s, gh_s);

    fuse_k<<<(N_NODES + 3) / 4, 256, 0, stream>>>(nodesB, gi_s, gh_s, msginB,
                                                  colsum, gamma, beta, out);
}